// Round 1
// 1034.570 us; speedup vs baseline: 1.7800x; 1.7800x over previous
//
#include <hip/hip_runtime.h>
#include <math.h>

// GumbelVQTokenizer: n=131072, d=128, num_code=512
// out = [quantized (n*128) | encodings (n*512) | indices-as-float (n)]  fp32
//
// Round 1: MFMA rewrite (split-bf16 emulated fp32).
//   prep_cb: 3-term bf16 split of codebook [code][dim] (GEMM1 B-frags) +
//            2-term transposed split [dim][code] (GEMM2 B-frags). 640 KB ws, L2-resident.
//   vq_main per 16-row block:
//     P0: load x, nudge, row-normalize, 3-term bf16 split -> LDS (padded stride 136)
//     G1: per wave 8 code-tiles: B-frags from L2, A-frags in regs, 24 mfma/tile
//         (x0c0,x1c1 | x0c1,x1c0 | x0c2,x2c0 -> 3 independent acc chains), logits->LDS
//     argmax(ab)+max(logit): 16-lane shuffle reduce + cross-wave LDS reduce
//     exp in place, packed as (bf16_hi<<16|bf16_lo) per f32 slot; row sums -> SInv
//     encodings write (reconstruct e = f32(lo)+f32(hi), *SInv, float4 coalesced)
//     G2: quantized = (E.cb)*SInv via mfma: E-frags unpacked from LDS with v_perm,
//         cbT0/cbT1 frags from L2, 3 mfma per (dim-tile, k-step), 6 acc chains.

#define N_TOK 131072
#define DIM   128
#define NC    512
#define RB    16
#define NBLK  (N_TOK / RB)        // 8192
#define EPSF  1e-6f
#define LP    516                 // logits row stride (f32): 516%8-groups -> conflict-free b128
#define XSP   136                 // x-split row stride (bf16): 272 B -> conflict-free b128

typedef unsigned short u16;
typedef __attribute__((ext_vector_type(8))) short bf16x8;   // 8 bf16 (4 VGPRs)
typedef __attribute__((ext_vector_type(4))) float f32x4;

__device__ __forceinline__ u16 f2bf(float f) {              // f32 -> bf16 RNE
    unsigned u = __float_as_uint(f);
    u += 0x7fffu + ((u >> 16) & 1u);
    return (u16)(u >> 16);
}
__device__ __forceinline__ float bf2f(u16 h) {
    return __uint_as_float(((unsigned)h) << 16);
}
__device__ __forceinline__ unsigned pack2(float e) {        // e -> lo:bf16(e), hi:bf16(residual)
    u16 h0 = f2bf(e);
    u16 h1 = f2bf(e - bf2f(h0));
    return (unsigned)h0 | ((unsigned)h1 << 16);
}

__global__ __launch_bounds__(256) void prep_cb(const float* __restrict__ cb,
    u16* __restrict__ c0, u16* __restrict__ c1, u16* __restrict__ c2,
    u16* __restrict__ t0, u16* __restrict__ t1)
{
    int idx = blockIdx.x * 256 + threadIdx.x;   // 0 .. 512*128-1
    int c = idx >> 7, k = idx & 127;
    float v = cb[idx];
    u16 b0 = f2bf(v);  float r1 = v - bf2f(b0);
    u16 b1 = f2bf(r1); float r2 = r1 - bf2f(b1);
    u16 b2 = f2bf(r2);
    c0[idx] = b0; c1[idx] = b1; c2[idx] = b2;
    t0[k * NC + c] = b0; t1[k * NC + c] = b1;
}

__global__ __launch_bounds__(256, 2) void vq_main(
    const float* __restrict__ x, const float* __restrict__ mask,
    const u16* __restrict__ cb0, const u16* __restrict__ cb1, const u16* __restrict__ cb2,
    const u16* __restrict__ cbT0, const u16* __restrict__ cbT1,
    const float* __restrict__ noise,
    float* __restrict__ out_q, float* __restrict__ out_e, float* __restrict__ out_i)
{
    __shared__ __align__(16) u16  xs0[RB][XSP];      // 4352 B each
    __shared__ __align__(16) u16  xs1[RB][XSP];
    __shared__ __align__(16) u16  xs2[RB][XSP];
    __shared__ __align__(16) float L[RB][LP];        // 33024 B; logits f32, later packed 2xbf16
    __shared__ float red[RB][33];
    __shared__ float wbv[4][RB]; __shared__ int wbi[4][RB]; __shared__ float wm[4][RB];
    __shared__ float Mrow[RB];  __shared__ float SInv[RB];

    const int tid  = threadIdx.x;
    const int row0 = blockIdx.x * RB;

    // ---------------- P0: load x tile, nudge, row-normalize, 3-way bf16 split ----------------
    float4 v[2]; int rA[2], qA[2];
#pragma unroll
    for (int i = 0; i < 2; ++i) {
        int g = tid + 256 * i, r = g >> 5, q = g & 31;  // 16 rows x 32 float4
        rA[i] = r; qA[i] = q;
        float4 t = reinterpret_cast<const float4*>(x)[(size_t)(row0 + r) * 32 + q];
        float nd = (1.0f - mask[row0 + r]) * EPSF;
        t.x += nd; t.y += nd; t.z += nd; t.w += nd;
        v[i] = t;
        red[r][q] = t.x*t.x + t.y*t.y + t.z*t.z + t.w*t.w;
    }
    __syncthreads();
    if (tid < RB) {
        float ss = 0.f;
#pragma unroll
        for (int j = 0; j < 32; ++j) ss += red[tid][j];
        SInv[tid] = 1.0f / fmaxf(sqrtf(ss), EPSF);   // temporarily inv_norm
    }
    __syncthreads();
#pragma unroll
    for (int i = 0; i < 2; ++i) {
        float inv = SInv[rA[i]];
        float4 t = v[i];
        float e0 = t.x*inv, e1 = t.y*inv, e2 = t.z*inv, e3 = t.w*inv;
        ushort4 s0, s1, s2;
        { u16 b = f2bf(e0); float r1 = e0-bf2f(b); u16 c = f2bf(r1); s0.x=b; s1.x=c; s2.x=f2bf(r1-bf2f(c)); }
        { u16 b = f2bf(e1); float r1 = e1-bf2f(b); u16 c = f2bf(r1); s0.y=b; s1.y=c; s2.y=f2bf(r1-bf2f(c)); }
        { u16 b = f2bf(e2); float r1 = e2-bf2f(b); u16 c = f2bf(r1); s0.z=b; s1.z=c; s2.z=f2bf(r1-bf2f(c)); }
        { u16 b = f2bf(e3); float r1 = e3-bf2f(b); u16 c = f2bf(r1); s0.w=b; s1.w=c; s2.w=f2bf(r1-bf2f(c)); }
        *reinterpret_cast<ushort4*>(&xs0[rA[i]][qA[i]*4]) = s0;
        *reinterpret_cast<ushort4*>(&xs1[rA[i]][qA[i]*4]) = s1;
        *reinterpret_cast<ushort4*>(&xs2[rA[i]][qA[i]*4]) = s2;
    }
    __syncthreads();

    const int w    = tid >> 6;        // wave 0..3
    const int lane = tid & 63;
    const int lr   = lane & 15;       // A/B frag: row/col-in-tile ; D frag: col
    const int lg   = lane >> 4;       // k-group

    // A fragments (reused across all 8 code-tiles of this wave)
    bf16x8 A0[4], A1[4], A2[4];
#pragma unroll
    for (int ks = 0; ks < 4; ++ks) {
        int ko = ks * 32 + lg * 8;
        A0[ks] = *reinterpret_cast<const bf16x8*>(&xs0[lr][ko]);
        A1[ks] = *reinterpret_cast<const bf16x8*>(&xs1[lr][ko]);
        A2[ks] = *reinterpret_cast<const bf16x8*>(&xs2[lr][ko]);
    }

    // ---------------- G1: ab = xn . cb^T via 6-term split-bf16 MFMA ----------------
    float bv[4], mx[4]; int bi[4];
#pragma unroll
    for (int r = 0; r < 4; ++r) { bv[r] = -1e30f; mx[r] = -1e30f; bi[r] = 0; }

    const int blofs = lr * DIM + lg * 8;                          // lane part of B-frag index
    const float* nzl = noise + ((size_t)row0 + lg * 4) * NC + lr; // lane part of noise addr

#pragma unroll
    for (int it = 0; it < 8; ++it) {
        const int c0 = (w * 8 + it) * 16;
        const u16* p0 = cb0 + c0 * DIM + blofs;
        const u16* p1 = cb1 + c0 * DIM + blofs;
        const u16* p2 = cb2 + c0 * DIM + blofs;
        bf16x8 B0[4], B1[4], B2[4];
#pragma unroll
        for (int ks = 0; ks < 4; ++ks) {
            B0[ks] = *reinterpret_cast<const bf16x8*>(p0 + ks * 32);
            B1[ks] = *reinterpret_cast<const bf16x8*>(p1 + ks * 32);
            B2[ks] = *reinterpret_cast<const bf16x8*>(p2 + ks * 32);
        }
        float nz[4];
#pragma unroll
        for (int r = 0; r < 4; ++r) nz[r] = nzl[(size_t)r * NC + c0];

        f32x4 ac0 = {0.f,0.f,0.f,0.f}, ac1 = {0.f,0.f,0.f,0.f}, ac2 = {0.f,0.f,0.f,0.f};
#pragma unroll
        for (int ks = 0; ks < 4; ++ks) ac0 = __builtin_amdgcn_mfma_f32_16x16x32_bf16(A0[ks], B0[ks], ac0, 0,0,0);
#pragma unroll
        for (int ks = 0; ks < 4; ++ks) ac0 = __builtin_amdgcn_mfma_f32_16x16x32_bf16(A1[ks], B1[ks], ac0, 0,0,0);
#pragma unroll
        for (int ks = 0; ks < 4; ++ks) ac1 = __builtin_amdgcn_mfma_f32_16x16x32_bf16(A0[ks], B1[ks], ac1, 0,0,0);
#pragma unroll
        for (int ks = 0; ks < 4; ++ks) ac1 = __builtin_amdgcn_mfma_f32_16x16x32_bf16(A1[ks], B0[ks], ac1, 0,0,0);
#pragma unroll
        for (int ks = 0; ks < 4; ++ks) ac2 = __builtin_amdgcn_mfma_f32_16x16x32_bf16(A0[ks], B2[ks], ac2, 0,0,0);
#pragma unroll
        for (int ks = 0; ks < 4; ++ks) ac2 = __builtin_amdgcn_mfma_f32_16x16x32_bf16(A2[ks], B0[ks], ac2, 0,0,0);
        f32x4 ab = (ac0 + ac1) + ac2;

#pragma unroll
        for (int r = 0; r < 4; ++r) {
            float a = ab[r];
            if (a > bv[r]) { bv[r] = a; bi[r] = c0 + lr; }    // strict > keeps lowest code
            float l = fmaf(2.f, a, nz[r]);
            mx[r] = fmaxf(mx[r], l);
            L[lg * 4 + r][c0 + lr] = l;                       // D-frag row=(lane>>4)*4+r, col=lane&15
        }
    }

    // 16-lane (code dim) shuffle reduce, then cross-wave LDS reduce
#pragma unroll
    for (int off = 1; off <= 8; off <<= 1) {
#pragma unroll
        for (int r = 0; r < 4; ++r) {
            float ov = __shfl_xor(bv[r], off);
            int   oi = __shfl_xor(bi[r], off);
            if (ov > bv[r] || (ov == bv[r] && oi < bi[r])) { bv[r] = ov; bi[r] = oi; }
            mx[r] = fmaxf(mx[r], __shfl_xor(mx[r], off));
        }
    }
    if (lr == 0) {
#pragma unroll
        for (int r = 0; r < 4; ++r) {
            int row = lg * 4 + r;
            wbv[w][row] = bv[r]; wbi[w][row] = bi[r]; wm[w][row] = mx[r];
        }
    }
    __syncthreads();
    if (tid < RB) {
        float B = -1e30f; int I = 0; float M = -1e30f;
#pragma unroll
        for (int ww = 0; ww < 4; ++ww) {
            float ov = wbv[ww][tid]; int oi = wbi[ww][tid];
            if (ov > B || (ov == B && oi < I)) { B = ov; I = oi; }
            M = fmaxf(M, wm[ww][tid]);
        }
        out_i[row0 + tid] = (float)I;
        Mrow[tid] = M;
    }
    __syncthreads();

    // ---------------- softmax: exp in place (packed 2xbf16 per slot), row sums ----------------
    {
        int r = tid >> 4, p = tid & 15;
        float M = Mrow[r];
        float lsum = 0.f;
        float4* lp = reinterpret_cast<float4*>(&L[r][p * 32]);
#pragma unroll
        for (int j = 0; j < 8; ++j) {
            float4 t = lp[j];
            float e0 = __expf(t.x - M), e1 = __expf(t.y - M);
            float e2 = __expf(t.z - M), e3 = __expf(t.w - M);
            lsum += (e0 + e1) + (e2 + e3);
            uint4 u;
            u.x = pack2(e0); u.y = pack2(e1); u.z = pack2(e2); u.w = pack2(e3);
            *reinterpret_cast<uint4*>(&lp[j]) = u;
        }
        red[r][p] = lsum;
    }
    __syncthreads();
    if (tid < RB) {
        float s = 0.f;
#pragma unroll
        for (int j = 0; j < 16; ++j) s += red[tid][j];
        SInv[tid] = 1.0f / s;
    }
    __syncthreads();

    // ---------------- encodings write (reconstruct f32, coalesced float4) ----------------
    {
        float4* eout = reinterpret_cast<float4*>(out_e + (size_t)row0 * NC);
#pragma unroll
        for (int i = 0; i < 8; ++i) {
            int g = tid + 256 * i;          // 0..2047 float4 over 16x512
            int row = g >> 7, c4 = g & 127;
            uint4 u = *reinterpret_cast<const uint4*>(&L[row][c4 * 4]);
            float inv = SInv[row];
            float4 o;
            o.x = (__uint_as_float(u.x << 16) + __uint_as_float(u.x & 0xffff0000u)) * inv;
            o.y = (__uint_as_float(u.y << 16) + __uint_as_float(u.y & 0xffff0000u)) * inv;
            o.z = (__uint_as_float(u.z << 16) + __uint_as_float(u.z & 0xffff0000u)) * inv;
            o.w = (__uint_as_float(u.w << 16) + __uint_as_float(u.w & 0xffff0000u)) * inv;
            eout[g] = o;
        }
    }

    // ---------------- G2: quantized = (E . cb) * SInv via 3-term split-bf16 MFMA ----------------
    {
        f32x4 aA[2], aB[2], aC[2];
#pragma unroll
        for (int t2 = 0; t2 < 2; ++t2) {
            aA[t2] = (f32x4){0.f,0.f,0.f,0.f};
            aB[t2] = (f32x4){0.f,0.f,0.f,0.f};
            aC[t2] = (f32x4){0.f,0.f,0.f,0.f};
        }
        const int tb = lr * NC + lg * 8;    // lane part of cbT frag index
#pragma unroll 4
        for (int ks = 0; ks < 16; ++ks) {
            const unsigned* Lr = reinterpret_cast<const unsigned*>(&L[lr][ks * 32 + lg * 8]);
            uint4 q0 = *reinterpret_cast<const uint4*>(Lr);
            uint4 q1 = *reinterpret_cast<const uint4*>(Lr + 4);
            uint4 d0, d1;                   // unpack: E0 = lo16 halves, E1 = hi16 halves
            d0.x = __builtin_amdgcn_perm(q0.y, q0.x, 0x05040100u);
            d0.y = __builtin_amdgcn_perm(q0.w, q0.z, 0x05040100u);
            d0.z = __builtin_amdgcn_perm(q1.y, q1.x, 0x05040100u);
            d0.w = __builtin_amdgcn_perm(q1.w, q1.z, 0x05040100u);
            d1.x = __builtin_amdgcn_perm(q0.y, q0.x, 0x07060302u);
            d1.y = __builtin_amdgcn_perm(q0.w, q0.z, 0x07060302u);
            d1.z = __builtin_amdgcn_perm(q1.y, q1.x, 0x07060302u);
            d1.w = __builtin_amdgcn_perm(q1.w, q1.z, 0x07060302u);
            bf16x8 e0 = __builtin_bit_cast(bf16x8, d0);
            bf16x8 e1 = __builtin_bit_cast(bf16x8, d1);
#pragma unroll
            for (int t2 = 0; t2 < 2; ++t2) {
                const int dt = w * 2 + t2;
                bf16x8 c0f = *reinterpret_cast<const bf16x8*>(cbT0 + dt * 16 * NC + ks * 32 + tb);
                bf16x8 c1f = *reinterpret_cast<const bf16x8*>(cbT1 + dt * 16 * NC + ks * 32 + tb);
                aA[t2] = __builtin_amdgcn_mfma_f32_16x16x32_bf16(e0, c0f, aA[t2], 0,0,0);
                aB[t2] = __builtin_amdgcn_mfma_f32_16x16x32_bf16(e0, c1f, aB[t2], 0,0,0);
                aC[t2] = __builtin_amdgcn_mfma_f32_16x16x32_bf16(e1, c0f, aC[t2], 0,0,0);
            }
        }
#pragma unroll
        for (int t2 = 0; t2 < 2; ++t2) {
            f32x4 qv = (aA[t2] + aB[t2]) + aC[t2];
            const int dcol = (w * 2 + t2) * 16 + lr;
#pragma unroll
            for (int r = 0; r < 4; ++r) {
                int row = lg * 4 + r;
                out_q[(size_t)(row0 + row) * DIM + dcol] = qv[r] * SInv[row];
            }
        }
    }
}

extern "C" void kernel_launch(void* const* d_in, const int* in_sizes, int n_in,
                              void* d_out, int out_size, void* d_ws, size_t ws_size,
                              hipStream_t stream)
{
    const float* x     = (const float*)d_in[0];
    const float* mask  = (const float*)d_in[1];
    const float* cb    = (const float*)d_in[2];
    const float* noise = (const float*)d_in[3];

    float* out_q = (float*)d_out;                       // n*128
    float* out_e = out_q + (size_t)N_TOK * DIM;         // n*512
    float* out_i = out_e + (size_t)N_TOK * NC;          // n (indices as float)

    u16* cb0  = (u16*)d_ws;                             // 5 x 128 KB = 640 KB workspace
    u16* cb1  = cb0 + 65536;
    u16* cb2  = cb1 + 65536;
    u16* cbT0 = cb2 + 65536;
    u16* cbT1 = cbT0 + 65536;

    hipLaunchKernelGGL(prep_cb, dim3(256), dim3(256), 0, stream, cb, cb0, cb1, cb2, cbT0, cbT1);
    hipLaunchKernelGGL(vq_main, dim3(NBLK), dim3(256), 0, stream,
                       x, mask, cb0, cb1, cb2, cbT0, cbT1, noise, out_q, out_e, out_i);
}